// Round 4
// baseline (17.332 us; speedup 1.0000x reference)
//
#include <hip/hip_runtime.h>

#define KDIM 2048
#define BDIM 32
#define W_RESOURCE 100.0f
#define CHUNKS 8     // i-chunks per batch; each block owns 256 consecutive i's
#define SLICES 16    // j-slices = waves per block
#define G 4          // i's per thread

__global__ __launch_bounds__(1024) void alloc_kernel(const float* __restrict__ values,
                                                     const float* __restrict__ weights,
                                                     float* __restrict__ out) {
    __shared__ float part[SLICES][256];

    const int b     = blockIdx.x >> 3;   // batch
    const int chunk = blockIdx.x & 7;    // 256-wide i chunk
    const int tid   = threadIdx.x;       // 0..1023
    const int lane  = tid & 63;
    const int slice = tid >> 6;          // wave id = j-slice

    const float* __restrict__ vrow = values  + (size_t)b * KDIM;
    const float* __restrict__ wrow = weights + (size_t)b * KDIM;

    // Per-thread i's: coalesced per-lane global loads (L2-hot, tiny).
    float vi[G], acc[G];
    #pragma unroll
    for (int g = 0; g < G; ++g) {
        vi[g]  = vrow[chunk * 256 + g * 64 + lane];
        acc[g] = 0.0f;
    }

    // j-slice: 128 j's = 32 float4 groups. Address is wave-uniform ->
    // scalar loads (s_load_dwordx4+) on the SMEM pipe, zero LDS, zero VALU.
    const float4* __restrict__ v4 = reinterpret_cast<const float4*>(vrow);
    const float4* __restrict__ w4 = reinterpret_cast<const float4*>(wrow);
    const int j4_begin = __builtin_amdgcn_readfirstlane(slice * (KDIM / 4 / SLICES));

    #pragma unroll 8
    for (int it = 0; it < KDIM / 4 / SLICES; ++it) {
        const float4 vj = v4[j4_begin + it];
        const float4 wj = w4[j4_begin + it];
        #pragma unroll
        for (int g = 0; g < G; ++g) {
            float a = acc[g];
            a += (vj.x >= vi[g]) ? wj.x : 0.0f;
            a += (vj.y >= vi[g]) ? wj.y : 0.0f;
            a += (vj.z >= vi[g]) ? wj.z : 0.0f;
            a += (vj.w >= vi[g]) ? wj.w : 0.0f;
            acc[g] = a;
        }
    }

    #pragma unroll
    for (int g = 0; g < G; ++g)
        part[slice][g * 64 + lane] = acc[g];
    __syncthreads();

    // Reduce 16 partials per i; threads 0..255 each own one i.
    if (tid < 256) {
        float load = 0.0f;
        #pragma unroll
        for (int s = 0; s < SLICES; ++s)
            load += part[s][tid];
        const int i = chunk * 256 + tid;
        out[(size_t)b * KDIM + i] = (W_RESOURCE - load >= 0.0f) ? wrow[i] : 0.0f;
    }
}

extern "C" void kernel_launch(void* const* d_in, const int* in_sizes, int n_in,
                              void* d_out, int out_size, void* d_ws, size_t ws_size,
                              hipStream_t stream) {
    const float* values  = (const float*)d_in[0];
    const float* weights = (const float*)d_in[1];
    float* out = (float*)d_out;

    dim3 grid(BDIM * CHUNKS);  // 256 blocks, 1 per CU
    dim3 block(1024);          // 16 waves = 16 j-slices
    alloc_kernel<<<grid, block, 0, stream>>>(values, weights, out);
}

// Round 5
// 13.222 us; speedup vs baseline: 1.3109x; 1.3109x over previous
//
#include <hip/hip_runtime.h>

#define KDIM 2048
#define BDIM 32
#define NB   4096           // 2^12 buckets: v*4096 is EXACT (mul by pow2), monotone
#define W_RESOURCE 100.0f

// inclusive prefix scan of one int per lane, within a wave
__device__ __forceinline__ int wave_prefix_incl_i(int v, int lane) {
    #pragma unroll
    for (int d = 1; d < 64; d <<= 1) {
        int o = __shfl_up(v, d);
        if (lane >= d) v += o;
    }
    return v;
}

// inclusive suffix scan of one float per lane, within a wave
__device__ __forceinline__ float wave_suffix_incl_f(float v, int lane) {
    #pragma unroll
    for (int d = 1; d < 64; d <<= 1) {
        float o = __shfl_down(v, d);
        if (lane + d < 64) v += o;
    }
    return v;
}

__global__ __launch_bounds__(1024) void alloc_kernel(const float* __restrict__ values,
                                                     const float* __restrict__ weights,
                                                     float* __restrict__ out) {
    __shared__ int   cnt[NB];      // histogram counts
    __shared__ int   start_[NB];   // bucket segment starts (excl prefix of cnt)
    __shared__ int   cursor[NB];   // scatter cursors -> segment ends after scatter
    __shared__ float bsum[NB];     // per-bucket weight sums (index order)
    __shared__ float suf[NB];      // inclusive suffix sums of bsum
    __shared__ float sv[KDIM];     // bucket-sorted values
    __shared__ float swt[KDIM];    // bucket-sorted weights
    __shared__ int   sidx[KDIM];   // original indices (sort key for determinism)
    __shared__ int   itmp[16];
    __shared__ float ftmp[16];

    const int b    = blockIdx.x;
    const int tid  = threadIdx.x;
    const int lane = tid & 63;
    const int wid  = tid >> 6;

    const float* __restrict__ vrow = values  + (size_t)b * KDIM;
    const float* __restrict__ wrow = weights + (size_t)b * KDIM;

    for (int u = tid; u < NB; u += 1024) cnt[u] = 0;

    // each thread owns elements tid and tid+1024 (coalesced loads)
    const float v0 = vrow[tid],        w0 = wrow[tid];
    const float v1 = vrow[tid + 1024], w1 = wrow[tid + 1024];
    int b0 = (int)(v0 * (float)NB); b0 = b0 > NB - 1 ? NB - 1 : b0;
    int b1 = (int)(v1 * (float)NB); b1 = b1 > NB - 1 ? NB - 1 : b1;
    __syncthreads();

    atomicAdd(&cnt[b0], 1);
    atomicAdd(&cnt[b1], 1);
    __syncthreads();

    // ---- exclusive prefix scan of cnt -> start_ / cursor (each thread owns 4 buckets)
    const int u0 = 4 * tid;
    const int c0 = cnt[u0], c1 = cnt[u0 + 1], c2 = cnt[u0 + 2], c3 = cnt[u0 + 3];
    const int lsum = c0 + c1 + c2 + c3;
    const int incl = wave_prefix_incl_i(lsum, lane);
    if (lane == 63) itmp[wid] = incl;          // wave total
    __syncthreads();
    if (tid == 0) {
        int s = 0;
        #pragma unroll
        for (int w = 0; w < 16; ++w) { int t = itmp[w]; itmp[w] = s; s += t; }
    }
    __syncthreads();
    const int excl = incl - lsum + itmp[wid];
    start_[u0]     = excl;                cursor[u0]     = excl;
    start_[u0 + 1] = excl + c0;           cursor[u0 + 1] = excl + c0;
    start_[u0 + 2] = excl + c0 + c1;      cursor[u0 + 2] = excl + c0 + c1;
    start_[u0 + 3] = excl + c0 + c1 + c2; cursor[u0 + 3] = excl + c0 + c1 + c2;
    __syncthreads();

    // ---- scatter (atomic slot grab; order fixed up by the index-sort below)
    const int p0 = atomicAdd(&cursor[b0], 1);
    sv[p0] = v0; swt[p0] = w0; sidx[p0] = tid;
    const int p1 = atomicAdd(&cursor[b1], 1);
    sv[p1] = v1; swt[p1] = w1; sidx[p1] = tid + 1024;
    __syncthreads();

    // ---- per-bucket: insertion-sort segment by original index (deterministic
    //      layout independent of atomic scatter order), sum weights in index order
    #pragma unroll
    for (int k = 0; k < 4; ++k) {
        const int u = u0 + k;
        const int s = start_[u], e = cursor[u];
        for (int x = s + 1; x < e; ++x) {
            const int ix = sidx[x]; const float vx = sv[x], wx = swt[x];
            int y = x - 1;
            while (y >= s && sidx[y] > ix) {
                sidx[y + 1] = sidx[y]; sv[y + 1] = sv[y]; swt[y + 1] = swt[y]; --y;
            }
            sidx[y + 1] = ix; sv[y + 1] = vx; swt[y + 1] = wx;
        }
        float acc = 0.0f;
        for (int x = s; x < e; ++x) acc += swt[x];
        bsum[u] = acc;
    }
    __syncthreads();

    // ---- inclusive suffix scan of bsum -> suf
    const float f0 = bsum[u0], f1 = bsum[u0 + 1], f2 = bsum[u0 + 2], f3 = bsum[u0 + 3];
    const float l3 = f3, l2 = f2 + l3, l1 = f1 + l2, l0 = f0 + l1;
    const float sincl = wave_suffix_incl_f(l0, lane);
    if (lane == 0) ftmp[wid] = sincl;          // wave total (suffix-incl at lane 0)
    __syncthreads();
    if (tid == 0) {
        float s = 0.0f;
        #pragma unroll
        for (int w = 15; w >= 0; --w) { float t = ftmp[w]; ftmp[w] = s; s += t; }
    }
    __syncthreads();
    const float sexcl = sincl - l0 + ftmp[wid];  // suffix strictly after my 4 buckets
    suf[u0]     = l0 + sexcl;
    suf[u0 + 1] = l1 + sexcl;
    suf[u0 + 2] = l2 + sexcl;
    suf[u0 + 3] = l3 + sexcl;
    __syncthreads();

    // ---- per-element: load = (buckets above) + (same-bucket exact compares)
    {
        float load = (b0 + 1 < NB) ? suf[b0 + 1] : 0.0f;
        const int s = start_[b0], e = cursor[b0];
        for (int p = s; p < e; ++p)
            if (sv[p] >= v0) load += swt[p];
        out[(size_t)b * KDIM + tid] = (W_RESOURCE - load >= 0.0f) ? w0 : 0.0f;
    }
    {
        float load = (b1 + 1 < NB) ? suf[b1 + 1] : 0.0f;
        const int s = start_[b1], e = cursor[b1];
        for (int p = s; p < e; ++p)
            if (sv[p] >= v1) load += swt[p];
        out[(size_t)b * KDIM + tid + 1024] = (W_RESOURCE - load >= 0.0f) ? w1 : 0.0f;
    }
}

extern "C" void kernel_launch(void* const* d_in, const int* in_sizes, int n_in,
                              void* d_out, int out_size, void* d_ws, size_t ws_size,
                              hipStream_t stream) {
    const float* values  = (const float*)d_in[0];
    const float* weights = (const float*)d_in[1];
    float* out = (float*)d_out;

    dim3 grid(BDIM);    // one block per batch
    dim3 block(1024);
    alloc_kernel<<<grid, block, 0, stream>>>(values, weights, out);
}

// Round 6
// 13.177 us; speedup vs baseline: 1.3154x; 1.0034x over previous
//
#include <hip/hip_runtime.h>

#define KDIM 2048
#define BDIM 32
#define NB   4096           // 2^12 buckets: v*4096 is EXACT (mul by pow2), monotone
#define W_RESOURCE 100.0f

// inclusive prefix scan of one int per lane, within a wave
__device__ __forceinline__ int wave_prefix_incl_i(int v, int lane) {
    #pragma unroll
    for (int d = 1; d < 64; d <<= 1) {
        int o = __shfl_up(v, d);
        if (lane >= d) v += o;
    }
    return v;
}

// inclusive suffix scan of one float per lane, within a wave
__device__ __forceinline__ float wave_suffix_incl_f(float v, int lane) {
    #pragma unroll
    for (int d = 1; d < 64; d <<= 1) {
        float o = __shfl_down(v, d);
        if (lane + d < 64) v += o;
    }
    return v;
}

__global__ __launch_bounds__(1024) void alloc_kernel(const float* __restrict__ values,
                                                     const float* __restrict__ weights,
                                                     float* __restrict__ out) {
    __shared__ int   cnt[NB];      // histogram counts
    __shared__ int   start_[NB];   // bucket segment starts (excl prefix of cnt)
    __shared__ int   cursor[NB];   // scatter cursors -> segment ends after scatter
    __shared__ float bsum[NB];     // per-bucket weight sums (index order)
    __shared__ float suf[NB];      // inclusive suffix sums of bsum
    __shared__ float sv[KDIM];     // bucket-sorted values
    __shared__ float swt[KDIM];    // bucket-sorted weights
    __shared__ int   sidx[KDIM];   // original indices (sort key for determinism)
    __shared__ int   itmp[16];
    __shared__ float ftmp[16];

    const int b    = blockIdx.x;
    const int tid  = threadIdx.x;
    const int lane = tid & 63;
    const int wid  = tid >> 6;

    const float* __restrict__ vrow = values  + (size_t)b * KDIM;
    const float* __restrict__ wrow = weights + (size_t)b * KDIM;

    // Issue global loads FIRST so HBM latency hides under the histogram clear.
    const float v0 = vrow[tid],        w0 = wrow[tid];
    const float v1 = vrow[tid + 1024], w1 = wrow[tid + 1024];

    for (int u = tid; u < NB; u += 1024) cnt[u] = 0;

    int b0 = (int)(v0 * (float)NB); b0 = b0 > NB - 1 ? NB - 1 : b0;
    int b1 = (int)(v1 * (float)NB); b1 = b1 > NB - 1 ? NB - 1 : b1;
    __syncthreads();

    atomicAdd(&cnt[b0], 1);
    atomicAdd(&cnt[b1], 1);
    __syncthreads();

    // ---- exclusive prefix scan of cnt -> start_ / cursor (4 buckets per thread)
    const int u0 = 4 * tid;
    const int c0 = cnt[u0], c1 = cnt[u0 + 1], c2 = cnt[u0 + 2], c3 = cnt[u0 + 3];
    const int lsum = c0 + c1 + c2 + c3;
    const int incl = wave_prefix_incl_i(lsum, lane);
    if (lane == 63) itmp[wid] = incl;          // wave total
    __syncthreads();
    if (wid == 0) {                            // wave-0 shuffle scan (was serial tid==0)
        int t = (lane < 16) ? itmp[lane] : 0;
        int ip = wave_prefix_incl_i(t, lane);
        if (lane < 16) itmp[lane] = ip - t;    // exclusive prefix of wave totals
    }
    __syncthreads();
    const int excl = incl - lsum + itmp[wid];
    start_[u0]     = excl;                cursor[u0]     = excl;
    start_[u0 + 1] = excl + c0;           cursor[u0 + 1] = excl + c0;
    start_[u0 + 2] = excl + c0 + c1;      cursor[u0 + 2] = excl + c0 + c1;
    start_[u0 + 3] = excl + c0 + c1 + c2; cursor[u0 + 3] = excl + c0 + c1 + c2;
    __syncthreads();

    // ---- scatter (atomic slot grab; order fixed up by the index-sort below)
    const int p0 = atomicAdd(&cursor[b0], 1);
    sv[p0] = v0; swt[p0] = w0; sidx[p0] = tid;
    const int p1 = atomicAdd(&cursor[b1], 1);
    sv[p1] = v1; swt[p1] = w1; sidx[p1] = tid + 1024;
    __syncthreads();

    // ---- per-bucket: insertion-sort segment by original index (deterministic
    //      layout independent of atomic scatter order), sum weights in index order
    #pragma unroll
    for (int k = 0; k < 4; ++k) {
        const int u = u0 + k;
        const int s = start_[u], e = cursor[u];
        for (int x = s + 1; x < e; ++x) {
            const int ix = sidx[x]; const float vx = sv[x], wx = swt[x];
            int y = x - 1;
            while (y >= s && sidx[y] > ix) {
                sidx[y + 1] = sidx[y]; sv[y + 1] = sv[y]; swt[y + 1] = swt[y]; --y;
            }
            sidx[y + 1] = ix; sv[y + 1] = vx; swt[y + 1] = wx;
        }
        float acc = 0.0f;
        for (int x = s; x < e; ++x) acc += swt[x];
        bsum[u] = acc;
    }
    __syncthreads();

    // ---- inclusive suffix scan of bsum -> suf
    const float f0 = bsum[u0], f1 = bsum[u0 + 1], f2 = bsum[u0 + 2], f3 = bsum[u0 + 3];
    const float l3 = f3, l2 = f2 + l3, l1 = f1 + l2, l0 = f0 + l1;
    const float sincl = wave_suffix_incl_f(l0, lane);
    if (lane == 0) ftmp[wid] = sincl;          // wave total (suffix-incl at lane 0)
    __syncthreads();
    if (wid == 0) {                            // wave-0 shuffle scan (was serial tid==0)
        float t = (lane < 16) ? ftmp[lane] : 0.0f;
        float si = wave_suffix_incl_f(t, lane);
        if (lane < 16) ftmp[lane] = si - t;    // exclusive suffix of wave totals
    }
    __syncthreads();
    const float sexcl = sincl - l0 + ftmp[wid];  // suffix strictly after my 4 buckets
    suf[u0]     = l0 + sexcl;
    suf[u0 + 1] = l1 + sexcl;
    suf[u0 + 2] = l2 + sexcl;
    suf[u0 + 3] = l3 + sexcl;
    __syncthreads();

    // ---- per-element: load = (buckets above) + (same-bucket exact compares)
    {
        float load = (b0 + 1 < NB) ? suf[b0 + 1] : 0.0f;
        const int s = start_[b0], e = cursor[b0];
        for (int p = s; p < e; ++p)
            if (sv[p] >= v0) load += swt[p];
        out[(size_t)b * KDIM + tid] = (W_RESOURCE - load >= 0.0f) ? w0 : 0.0f;
    }
    {
        float load = (b1 + 1 < NB) ? suf[b1 + 1] : 0.0f;
        const int s = start_[b1], e = cursor[b1];
        for (int p = s; p < e; ++p)
            if (sv[p] >= v1) load += swt[p];
        out[(size_t)b * KDIM + tid + 1024] = (W_RESOURCE - load >= 0.0f) ? w1 : 0.0f;
    }
}

extern "C" void kernel_launch(void* const* d_in, const int* in_sizes, int n_in,
                              void* d_out, int out_size, void* d_ws, size_t ws_size,
                              hipStream_t stream) {
    const float* values  = (const float*)d_in[0];
    const float* weights = (const float*)d_in[1];
    float* out = (float*)d_out;

    dim3 grid(BDIM);    // one block per batch
    dim3 block(1024);
    alloc_kernel<<<grid, block, 0, stream>>>(values, weights, out);
}